// Round 3
// baseline (647.102 us; speedup 1.0000x reference)
//
#include <hip/hip_runtime.h>

#define F1260 1260

__device__ __forceinline__ float leakyf(float x) { return x >= 0.f ? x : 0.2f * x; }
__device__ __forceinline__ float eluf(float x) { return x > 0.f ? x : expm1f(x); }
__device__ __forceinline__ float sigmoidf(float x) { return 1.f / (1.f + __expf(-x)); }

// ws float-offset map (total < 56 KB):
//   0..1259   : fsum per flat-feature f      (atomic accum, memset to 0)
//   1280..2539: fsq per flat-feature f
//   2560: scale[42]     2624: shift[42]
//   2688: adjn[7][49]   (6 GAT1 heads + GAT2 head0)
//   3072: WA1[6][3][180] (si-fold, sj-fold, We column)
//   6400: WA2[3][30]
//   13600: bias[84] (b_ih+b_hh)  13700: Wout[147]  13860: bout[7]

// ---------------- kA: BN stats, float4-coalesced ----------------
// 320 threads (315 active), thread owns float4 column t, loops 128 rows.
__global__ __launch_bounds__(320) void kA_stats(const float* __restrict__ x,
                                                float* __restrict__ ws, int N) {
    const int t = threadIdx.x;
    if (t >= 315) return;
    const int n0 = blockIdx.x * 128;
    const int f0 = t * 4;
    float s[4] = {0.f, 0.f, 0.f, 0.f}, q[4] = {0.f, 0.f, 0.f, 0.f};
    for (int i = 0; i < 128; ++i) {
        const float4 a = *(const float4*)(x + (size_t)(n0 + i) * F1260 + f0);
        s[0] += a.x; q[0] += a.x * a.x;
        s[1] += a.y; q[1] += a.y * a.y;
        s[2] += a.z; q[2] += a.z * a.z;
        s[3] += a.w; q[3] += a.w * a.w;
    }
#pragma unroll
    for (int j = 0; j < 4; ++j) {
        atomicAdd(&ws[f0 + j], s[j]);
        atomicAdd(&ws[1280 + f0 + j], q[j]);
    }
}

// ---------------- kB: finalize BN, adjacency norm, weight folds ----------------
__global__ __launch_bounds__(256) void kB_setup(
        const float* __restrict__ bn_gamma, const float* __restrict__ bn_beta,
        const float* __restrict__ W1, const float* __restrict__ a1, const float* __restrict__ B1,
        const float* __restrict__ W2, const float* __restrict__ a2, const float* __restrict__ B2,
        const float* __restrict__ b_ih, const float* __restrict__ b_hh,
        const float* __restrict__ W_out, const float* __restrict__ b_out,
        float* __restrict__ ws, int N) {
    const int t = threadIdx.x;
    const int HH[6] = {0, 3, 6, 10, 13, 16};
    const int EH[6] = {0, 3, 6, 0, 3, 6};

    // per-channel BN scale/shift; channel ch = v*6 + c; flat f = c*210 + tt*7 + v
    if (t < 42) {
        const int v = t / 6, c = t % 6;
        float s = 0.f, q = 0.f;
        for (int tt = 0; tt < 30; ++tt) {
            const int f = c * 210 + tt * 7 + v;
            s += ws[f];
            q += ws[1280 + f];
        }
        const float cnt = 30.f * (float)N;
        const float mean = s / cnt;
        const float var = q / cnt - mean * mean;
        const float sc = bn_gamma[t] * rsqrtf(var + 1e-5f);
        ws[2560 + t] = sc;
        ws[2624 + t] = bn_beta[t] - mean * sc;
    }
    // normalized adjacency: 6 GAT1 heads + GAT2 head0
    if (t >= 64 && t < 71) {
        const int idx = t - 64;
        const float* Bp = (idx < 6) ? (B1 + HH[idx] * 49) : B2;
        float* op = ws + 2688 + idx * 49;
        float adj[49];
        for (int i = 0; i < 49; ++i) adj[i] = Bp[i];
        for (int i = 0; i < 7; ++i) adj[i * 8] += 1.f;
        float mn = adj[0], mx = adj[0];
        for (int i = 1; i < 49; ++i) { mn = fminf(mn, adj[i]); mx = fmaxf(mx, adj[i]); }
        const float inv = 1.f / (mx - mn);
        float rinv[7];
        for (int i = 0; i < 7; ++i) {
            float rs = 0.f;
            for (int j = 0; j < 7; ++j) { adj[i * 7 + j] = (adj[i * 7 + j] - mn) * inv; rs += adj[i * 7 + j]; }
            rinv[i] = rsqrtf(rs);
        }
        for (int i = 0; i < 7; ++i)
            for (int j = 0; j < 7; ++j)
                op[i * 7 + j] = adj[i * 7 + j] * rinv[i] * rinv[j];
    }
    // WA1: fold a1 into W1 for the 6 live heads (+ keep the needed We column)
    for (int task = t; task < 6 * 180; task += 256) {
        const int hh = task / 180, k = task % 180;
        const int h = HH[hh];
        const float* Wp = W1 + ((size_t)h * 180 + k) * 9;
        float si = 0.f, sj = 0.f;
        for (int e = 0; e < 9; ++e) {
            const float w = Wp[e];
            si += w * a1[h * 18 + e];
            sj += w * a1[h * 18 + 9 + e];
        }
        ws[3072 + hh * 540 + k] = si;
        ws[3072 + hh * 540 + 180 + k] = sj;
        ws[3072 + hh * 540 + 360 + k] = Wp[EH[hh]];
    }
    // WA2: head 0 of l2 (f=0 column kept)
    if (t < 30) {
        const float* Wp = W2 + t * 10;
        float si = 0.f, sj = 0.f;
        for (int f = 0; f < 10; ++f) {
            const float w = Wp[f];
            si += w * a2[f];
            sj += w * a2[10 + f];
        }
        ws[6400 + t] = si;
        ws[6400 + 30 + t] = sj;
        ws[6400 + 60 + t] = Wp[0];
    }
    if (t < 84) ws[13600 + t] = b_ih[t] + b_hh[t];
    if (t < 147) ws[13700 + t] = W_out[t];
    if (t < 7) ws[13860 + t] = b_out[t];
}

// ---------------- kC: fused dots + attention + LSTM + out ----------------
// 128 threads, 16 samples per block. x staged in two 630-float half-rows.
#define S_STAGE 0            // float [16][632]  (40448 B) -- overlaid later by:
#define S_XS0   0            //   float [16][85]   (5440 B)
#define S_H2T   5440         //   float [16][42]   (2688 B)
#define S_H1    8128         //   float [16][22]   (1408 B)
#define S_RES   40448        // float [16][253] (16192 B)
#define S_SCSH  56640        // float [84]
#define S_ADJ   56976        // float [343]
#define S_TOTAL 58368

__global__ __launch_bounds__(128) void kC_main(const float* __restrict__ x,
        const float* __restrict__ ws, const float* __restrict__ Wih,
        float* __restrict__ outp, int N) {
    __shared__ __align__(16) char smem[S_TOTAL];
    const int t = threadIdx.x;
    const int n0 = blockIdx.x * 16;

    float* stage = (float*)(smem + S_STAGE);
    float* res = (float*)(smem + S_RES);
    float* scsh = (float*)(smem + S_SCSH);
    float* adjL = (float*)(smem + S_ADJ);

    // ---- phase 0: params ----
    if (t < 84) scsh[t] = ws[2560 + (t < 42 ? t : 22 + t)];  // [0..41]=scale, [42..83]=shift
    for (int i = t; i < 343; i += 128) adjL[i] = ws[2688 + i];

    // ---- phase 1: dots over two half-row chunks; thread = (v, nl), 112 active ----
    const int v = t >> 4, nl = t & 15;
    float s1[18];
#pragma unroll
    for (int i = 0; i < 18; ++i) s1[i] = 0.f;
    const float* WA1 = ws + 3072;
    const float* WA2 = ws + 6400;

    for (int half = 0; half < 2; ++half) {
        __syncthreads();   // protect stage from previous phase's readers
        for (int idx = t; idx < 16 * 315; idx += 128) {
            const int row = idx / 315;
            const int col2 = (idx % 315) * 2;
            const float2 val = *(const float2*)(x + (size_t)(n0 + row) * F1260 + half * 630 + col2);
            *(float2*)(stage + row * 632 + col2) = val;
        }
        __syncthreads();
        if (t < 112) {
            const float* xr = stage + nl * 632;
            for (int cc = 0; cc < 3; ++cc) {
                const int c = half * 3 + cc;
                const float sc = scsh[v * 6 + c];
                const float sh = scsh[42 + v * 6 + c];
                float g0 = 0.f, g1 = 0.f, g2 = 0.f;
                for (int tt = 0; tt < 30; ++tt) {
                    const float a = xr[cc * 210 + tt * 7 + v] * sc + sh;
                    const int k = c * 30 + tt;
#pragma unroll
                    for (int hh = 0; hh < 6; ++hh) {
                        s1[hh * 3 + 0] += a * WA1[hh * 540 + k];
                        s1[hh * 3 + 1] += a * WA1[hh * 540 + 180 + k];
                        s1[hh * 3 + 2] += a * WA1[hh * 540 + 360 + k];
                    }
                    g0 += a * WA2[tt];
                    g1 += a * WA2[30 + tt];
                    g2 += a * WA2[60 + tt];
                }
                float* rp = res + nl * 253 + 126 + (v * 6 + c) * 3;
                rp[0] = g0; rp[1] = g1; rp[2] = g2;
            }
        }
    }
    if (t < 112) {
#pragma unroll
        for (int q = 0; q < 18; ++q)
            res[nl * 253 + v * 18 + q] = s1[q];
    }
    __syncthreads();

    float* xs0 = (float*)(smem + S_XS0);
    float* h2t = (float*)(smem + S_H2T);

    // ---- phase 2: GAT1 heads; thread = (hh, nl), 96 active ----
    if (t < 96) {
        const int hh = t >> 4, nl2 = t & 15;
        float si[7], sj[7], we[7];
#pragma unroll
        for (int vv = 0; vv < 7; ++vv) {
            const float* rp = res + nl2 * 253 + vv * 18 + hh * 3;
            si[vv] = rp[0]; sj[vv] = rp[1]; we[vv] = rp[2];
        }
        float mxsj = sj[0];
#pragma unroll
        for (int j = 1; j < 7; ++j) mxsj = fmaxf(mxsj, sj[j]);
        float p[7];
#pragma unroll
        for (int i = 0; i < 7; ++i) {
            const float m = leakyf(si[i] + mxsj);   // leaky monotonic -> row max
            float den = 0.f, num = 0.f;
#pragma unroll
            for (int j = 0; j < 7; ++j) {
                const float w = __expf(leakyf(si[i] + sj[j]) - m);
                den += w;
                num += w * we[j];
            }
            p[i] = num / den;
        }
        const float* An = adjL + hh * 49;
#pragma unroll
        for (int i = 0; i < 7; ++i) {
            float r = 0.f;
#pragma unroll
            for (int k = 0; k < 7; ++k) r += An[i * 7 + k] * p[k];
            xs0[nl2 * 85 + hh * 7 + i] = eluf(r);
        }
    }
    // ---- phase 2b: GAT2 softmax-over-channels; thread = (i, nl), 112 active ----
    if (t < 112) {
        const int i = t >> 4, nl2 = t & 15;
        float si2[6];
#pragma unroll
        for (int c = 0; c < 6; ++c)
            si2[c] = res[nl2 * 253 + 126 + (i * 6 + c) * 3];
        float hc[6];
#pragma unroll
        for (int c = 0; c < 6; ++c) hc[c] = 0.f;
#pragma unroll
        for (int j = 0; j < 7; ++j) {
            float s[6];
            float m = -1e30f;
#pragma unroll
            for (int c = 0; c < 6; ++c) {
                const float* rp = res + nl2 * 253 + 126 + (j * 6 + c) * 3;
                s[c] = leakyf(si2[c] + rp[1]);
                m = fmaxf(m, s[c]);
            }
            float den = 0.f;
#pragma unroll
            for (int c = 0; c < 6; ++c) { s[c] = __expf(s[c] - m); den += s[c]; }
            const float rd = 1.f / den;
#pragma unroll
            for (int c = 0; c < 6; ++c) {
                const float wh0 = res[nl2 * 253 + 126 + (j * 6 + c) * 3 + 2];
                hc[c] += wh0 * s[c] * rd;
            }
        }
#pragma unroll
        for (int c = 0; c < 6; ++c)
            h2t[nl2 * 42 + i * 6 + c] = hc[c];
    }
    __syncthreads();

    // ---- phase 3: GAT2 adj multiply; thread = (c, nl), 96 active ----
    if (t < 96) {
        const int c = t >> 4, nl2 = t & 15;
        const float* An2 = adjL + 6 * 49;
        float h[7];
#pragma unroll
        for (int u = 0; u < 7; ++u) h[u] = h2t[nl2 * 42 + u * 6 + c];
#pragma unroll
        for (int vv = 0; vv < 7; ++vv) {
            float r = 0.f;
#pragma unroll
            for (int u = 0; u < 7; ++u) r += h[u] * An2[u * 7 + vv];
            xs0[nl2 * 85 + 42 + c * 7 + vv] = eluf(r);
        }
    }
    __syncthreads();

    // ---- phase 4: LSTM step 0; thread = (g8, nl), all 128 ----
    float* h1s = (float*)(smem + S_H1);
    {
        const int g8 = t >> 4, nl2 = t & 15;
        const float* bias = ws + 13600;
        const float* xsp = xs0 + nl2 * 85;
        for (int gi = g8; gi < 21; gi += 8) {
            float ga = bias[gi], gg = bias[42 + gi], go = bias[63 + gi];
#pragma unroll
            for (int k = 0; k < 84; ++k) {
                const float xv = xsp[k];
                ga += xv * Wih[gi * 84 + k];
                gg += xv * Wih[(42 + gi) * 84 + k];
                go += xv * Wih[(63 + gi) * 84 + k];
            }
            const float c1 = sigmoidf(ga) * tanhf(gg);
            h1s[nl2 * 22 + gi] = sigmoidf(go) * tanhf(c1);
        }
    }
    __syncthreads();

    // ---- phase 5: output projection; thread = nl*7+j, 112 active, coalesced ----
    if (t < 112) {
        const int nl2 = t / 7, j = t - nl2 * 7;
        const float* Wout = ws + 13700;
        float r = ws[13860 + j];
#pragma unroll
        for (int m = 0; m < 21; ++m) r += h1s[nl2 * 22 + m] * Wout[j * 21 + m];
        outp[(size_t)n0 * 7 + t] = r;
    }
}

extern "C" void kernel_launch(void* const* d_in, const int* in_sizes, int n_in,
                              void* d_out, int out_size, void* d_ws, size_t ws_size,
                              hipStream_t stream) {
    const int N = in_sizes[0] / F1260;

    const float* x        = (const float*)d_in[0];
    const float* bn_gamma = (const float*)d_in[1];
    const float* bn_beta  = (const float*)d_in[2];
    const float* W1       = (const float*)d_in[3];
    const float* a1       = (const float*)d_in[4];
    const float* B1       = (const float*)d_in[5];
    const float* W2       = (const float*)d_in[6];
    const float* a2       = (const float*)d_in[7];
    const float* B2       = (const float*)d_in[8];
    const float* W_ih     = (const float*)d_in[9];
    // d_in[10] = W_hh unused (h0 = 0 -> only LSTM step 0 matters)
    const float* b_ih     = (const float*)d_in[11];
    const float* b_hh     = (const float*)d_in[12];
    const float* W_out    = (const float*)d_in[13];
    const float* b_out    = (const float*)d_in[14];

    float* wsf = (float*)d_ws;

    hipMemsetAsync(d_ws, 0, 2560 * sizeof(float), stream);   // zero fsum/fsq

    kA_stats<<<dim3(N / 128), dim3(320), 0, stream>>>(x, wsf, N);
    kB_setup<<<dim3(1), dim3(256), 0, stream>>>(bn_gamma, bn_beta, W1, a1, B1,
                                                W2, a2, B2, b_ih, b_hh,
                                                W_out, b_out, wsf, N);
    kC_main<<<dim3(N / 16), dim3(128), 0, stream>>>(x, wsf, W_ih, (float*)d_out, N);
}

// Round 5
// 577.318 us; speedup vs baseline: 1.1209x; 1.1209x over previous
//
#include <hip/hip_runtime.h>

#define F1260 1260

__device__ __forceinline__ float leakyf(float x) { return x >= 0.f ? x : 0.2f * x; }
__device__ __forceinline__ float eluf(float x) { return x > 0.f ? x : expm1f(x); }
__device__ __forceinline__ float sigmoidf(float x) { return 1.f / (1.f + __expf(-x)); }

// ws float-offset map (total < 60 KB):
//   0..1259   : fsum per flat-feature f      (atomic accum, memset to 0)
//   1280..2539: fsq per flat-feature f
//   2560: scale[42]     2624: shift[42]
//   2688: adjn[7][49]   (6 GAT1 heads + GAT2 head0)
//   3072: WB[180][24]   (per k=c*30+tt: [0..17]=GAT1 hh*3+{si,sj,we},
//                        [18..20]={a2si[tt],a2sj[tt],W2[tt][0]}, 3 pad) -> 7392
//   13600: bias[84] (b_ih+b_hh)  13700: Wout[147]  13860: bout[7]

// ---------------- kA: BN stats, float4-coalesced, 32 rows/block ----------------
__global__ __launch_bounds__(320) void kA_stats(const float* __restrict__ x,
                                                float* __restrict__ ws, int N) {
    const int t = threadIdx.x;
    if (t >= 315) return;
    const int n0 = blockIdx.x * 32;
    const int f0 = t * 4;
    float s[4] = {0.f, 0.f, 0.f, 0.f}, q[4] = {0.f, 0.f, 0.f, 0.f};
#pragma unroll 4
    for (int i = 0; i < 32; ++i) {
        const float4 a = *(const float4*)(x + (size_t)(n0 + i) * F1260 + f0);
        s[0] += a.x; q[0] += a.x * a.x;
        s[1] += a.y; q[1] += a.y * a.y;
        s[2] += a.z; q[2] += a.z * a.z;
        s[3] += a.w; q[3] += a.w * a.w;
    }
#pragma unroll
    for (int j = 0; j < 4; ++j) {
        atomicAdd(&ws[f0 + j], s[j]);
        atomicAdd(&ws[1280 + f0 + j], q[j]);
    }
}

// ---------------- kB: finalize BN, adjacency norm, weight folds ----------------
__global__ __launch_bounds__(256) void kB_setup(
        const float* __restrict__ bn_gamma, const float* __restrict__ bn_beta,
        const float* __restrict__ W1, const float* __restrict__ a1, const float* __restrict__ B1,
        const float* __restrict__ W2, const float* __restrict__ a2, const float* __restrict__ B2,
        const float* __restrict__ b_ih, const float* __restrict__ b_hh,
        const float* __restrict__ W_out, const float* __restrict__ b_out,
        float* __restrict__ ws, int N) {
    const int t = threadIdx.x;
    const int HH[6] = {0, 3, 6, 10, 13, 16};
    const int EH[6] = {0, 3, 6, 0, 3, 6};

    // per-channel BN scale/shift; channel ch = v*6 + c; flat f = c*210 + tt*7 + v
    if (t < 42) {
        const int v = t / 6, c = t % 6;
        float s = 0.f, q = 0.f;
        for (int tt = 0; tt < 30; ++tt) {
            const int f = c * 210 + tt * 7 + v;
            s += ws[f];
            q += ws[1280 + f];
        }
        const float cnt = 30.f * (float)N;
        const float mean = s / cnt;
        const float var = q / cnt - mean * mean;
        const float sc = bn_gamma[t] * rsqrtf(var + 1e-5f);
        ws[2560 + t] = sc;
        ws[2624 + t] = bn_beta[t] - mean * sc;
    }
    // normalized adjacency: 6 GAT1 heads + GAT2 head0
    if (t >= 64 && t < 71) {
        const int idx = t - 64;
        const float* Bp = (idx < 6) ? (B1 + HH[idx] * 49) : B2;
        float* op = ws + 2688 + idx * 49;
        float adj[49];
        for (int i = 0; i < 49; ++i) adj[i] = Bp[i];
        for (int i = 0; i < 7; ++i) adj[i * 8] += 1.f;
        float mn = adj[0], mx = adj[0];
        for (int i = 1; i < 49; ++i) { mn = fminf(mn, adj[i]); mx = fmaxf(mx, adj[i]); }
        const float inv = 1.f / (mx - mn);
        float rinv[7];
        for (int i = 0; i < 7; ++i) {
            float rs = 0.f;
            for (int j = 0; j < 7; ++j) { adj[i * 7 + j] = (adj[i * 7 + j] - mn) * inv; rs += adj[i * 7 + j]; }
            rinv[i] = rsqrtf(rs);
        }
        for (int i = 0; i < 7; ++i)
            for (int j = 0; j < 7; ++j)
                op[i * 7 + j] = adj[i * 7 + j] * rinv[i] * rinv[j];
    }
    // WB: fold a1 into W1 for the 6 live heads, repacked per-k
    for (int task = t; task < 6 * 180; task += 256) {
        const int hh = task / 180, k = task % 180;
        const int h = HH[hh];
        const float* Wp = W1 + ((size_t)h * 180 + k) * 9;
        float si = 0.f, sj = 0.f;
        for (int e = 0; e < 9; ++e) {
            const float w = Wp[e];
            si += w * a1[h * 18 + e];
            sj += w * a1[h * 18 + 9 + e];
        }
        ws[3072 + k * 24 + hh * 3 + 0] = si;
        ws[3072 + k * 24 + hh * 3 + 1] = sj;
        ws[3072 + k * 24 + hh * 3 + 2] = Wp[EH[hh]];
    }
    // WA2 slots (replicated per c): head 0 of l2, f=0 column kept
    if (t < 30) {
        const float* Wp = W2 + t * 10;
        float si = 0.f, sj = 0.f;
        for (int f = 0; f < 10; ++f) {
            const float w = Wp[f];
            si += w * a2[f];
            sj += w * a2[10 + f];
        }
        for (int c = 0; c < 6; ++c) {
            const int k = c * 30 + t;
            ws[3072 + k * 24 + 18] = si;
            ws[3072 + k * 24 + 19] = sj;
            ws[3072 + k * 24 + 20] = Wp[0];
        }
    }
    if (t < 84) ws[13600 + t] = b_ih[t] + b_hh[t];
    if (t < 147) ws[13700 + t] = W_out[t];
    if (t < 7) ws[13860 + t] = b_out[t];
}

// ---------------- kC: fused dots + attention + LSTM + out ----------------
// 128 threads, 16 samples per block, per-c staging (6 rounds).
// LDS = 31340 B -> 5 blocks/CU (10 waves/CU).
#define ST_STRIDE 210        // 210 % 32 == 18 -> 2-way bank aliasing (free)
#define RS_STRIDE 253        // odd -> conflict-free; row needs 252 floats!
#define S_STAGE 0            // float [16][210]  (13440 B) -- overlaid later by:
#define S_XS0   0            //   float [16][85]   (5440 B)
#define S_H2T   5440         //   float [16][42]   (2688 B)
#define S_H1    8128         //   float [16][22]   (1408 B)
#define S_RES   13440        // float [16][253] (16192 B)
#define S_SCSH  29632        // float [84]
#define S_ADJ   29968        // float [343]
#define S_TOTAL 31340

__global__ __launch_bounds__(128) void kC_main(const float* __restrict__ x,
        const float* __restrict__ ws, const float* __restrict__ Wih,
        float* __restrict__ outp, int N) {
    __shared__ __align__(16) char smem[S_TOTAL];
    const int t = threadIdx.x;
    const int n0 = blockIdx.x * 16;

    float* stage = (float*)(smem + S_STAGE);
    float* res = (float*)(smem + S_RES);
    float* scsh = (float*)(smem + S_SCSH);
    float* adjL = (float*)(smem + S_ADJ);

    // ---- phase 0: params ----
    if (t < 84) scsh[t] = ws[2560 + (t < 42 ? t : 22 + t)];  // [0..41]=scale, [42..83]=shift
    for (int i = t; i < 343; i += 128) adjL[i] = ws[2688 + i];

    // ---- phase 1: dots over six c-chunks; thread = (v, nl), 112 active ----
    const int v = t >> 4, nl = t & 15;
    float s1[18];
#pragma unroll
    for (int i = 0; i < 18; ++i) s1[i] = 0.f;
    const float* WB = ws + 3072;

    for (int c = 0; c < 6; ++c) {
        __syncthreads();   // protect stage from previous round's readers
        for (int idx = t; idx < 16 * 105; idx += 128) {
            const int row = idx / 105;
            const int col2 = (idx % 105) * 2;
            const float2 val = *(const float2*)(x + (size_t)(n0 + row) * F1260 + c * 210 + col2);
            *(float2*)(stage + row * ST_STRIDE + col2) = val;
        }
        __syncthreads();
        if (v < 7) {
            const float sc = scsh[v * 6 + c];
            const float sh = scsh[42 + v * 6 + c];
            const float* xr = stage + nl * ST_STRIDE + v;
            const float* wb = WB + (c * 30) * 24;
            float g0 = 0.f, g1 = 0.f, g2 = 0.f;
#pragma unroll
            for (int tt = 0; tt < 30; ++tt) {
                const float a = xr[tt * 7] * sc + sh;
                const float* w = wb + tt * 24;
#pragma unroll
                for (int q = 0; q < 18; ++q) s1[q] += a * w[q];
                g0 += a * w[18];
                g1 += a * w[19];
                g2 += a * w[20];
            }
            float* rp = res + nl * RS_STRIDE + 126 + (v * 6 + c) * 3;
            rp[0] = g0; rp[1] = g1; rp[2] = g2;
        }
    }
    if (v < 7) {
#pragma unroll
        for (int q = 0; q < 18; ++q)
            res[nl * RS_STRIDE + v * 18 + q] = s1[q];
    }
    __syncthreads();

    float* xs0 = (float*)(smem + S_XS0);
    float* h2t = (float*)(smem + S_H2T);

    // ---- phase 2: GAT1 heads; thread = (hh, nl), 96 active ----
    if (t < 96) {
        const int hh = t >> 4, nl2 = t & 15;
        float si[7], sj[7], we[7];
#pragma unroll
        for (int vv = 0; vv < 7; ++vv) {
            const float* rp = res + nl2 * RS_STRIDE + vv * 18 + hh * 3;
            si[vv] = rp[0]; sj[vv] = rp[1]; we[vv] = rp[2];
        }
        float mxsj = sj[0];
#pragma unroll
        for (int j = 1; j < 7; ++j) mxsj = fmaxf(mxsj, sj[j]);
        float p[7];
#pragma unroll
        for (int i = 0; i < 7; ++i) {
            const float m = leakyf(si[i] + mxsj);   // leaky monotonic -> row max
            float den = 0.f, num = 0.f;
#pragma unroll
            for (int j = 0; j < 7; ++j) {
                const float w = __expf(leakyf(si[i] + sj[j]) - m);
                den += w;
                num += w * we[j];
            }
            p[i] = num / den;
        }
        const float* An = adjL + hh * 49;
#pragma unroll
        for (int i = 0; i < 7; ++i) {
            float r = 0.f;
#pragma unroll
            for (int k = 0; k < 7; ++k) r += An[i * 7 + k] * p[k];
            xs0[nl2 * 85 + hh * 7 + i] = eluf(r);
        }
    }
    // ---- phase 2b: GAT2 softmax-over-channels; thread = (i, nl), 112 active ----
    if (t < 112) {
        const int i = t >> 4, nl2 = t & 15;
        float si2[6];
#pragma unroll
        for (int c = 0; c < 6; ++c)
            si2[c] = res[nl2 * RS_STRIDE + 126 + (i * 6 + c) * 3];
        float hc[6];
#pragma unroll
        for (int c = 0; c < 6; ++c) hc[c] = 0.f;
#pragma unroll
        for (int j = 0; j < 7; ++j) {
            float s[6];
            float m = -1e30f;
#pragma unroll
            for (int c = 0; c < 6; ++c) {
                const float* rp = res + nl2 * RS_STRIDE + 126 + (j * 6 + c) * 3;
                s[c] = leakyf(si2[c] + rp[1]);
                m = fmaxf(m, s[c]);
            }
            float den = 0.f;
#pragma unroll
            for (int c = 0; c < 6; ++c) { s[c] = __expf(s[c] - m); den += s[c]; }
            const float rd = 1.f / den;
#pragma unroll
            for (int c = 0; c < 6; ++c) {
                const float wh0 = res[nl2 * RS_STRIDE + 126 + (j * 6 + c) * 3 + 2];
                hc[c] += wh0 * s[c] * rd;
            }
        }
#pragma unroll
        for (int c = 0; c < 6; ++c)
            h2t[nl2 * 42 + i * 6 + c] = hc[c];
    }
    __syncthreads();

    // ---- phase 3: GAT2 adj multiply; thread = (c, nl), 96 active ----
    if (t < 96) {
        const int c = t >> 4, nl2 = t & 15;
        const float* An2 = adjL + 6 * 49;
        float h[7];
#pragma unroll
        for (int u = 0; u < 7; ++u) h[u] = h2t[nl2 * 42 + u * 6 + c];
#pragma unroll
        for (int vv = 0; vv < 7; ++vv) {
            float r = 0.f;
#pragma unroll
            for (int u = 0; u < 7; ++u) r += h[u] * An2[u * 7 + vv];
            xs0[nl2 * 85 + 42 + c * 7 + vv] = eluf(r);
        }
    }
    __syncthreads();

    // ---- phase 4: LSTM step 0; thread = (g8, nl), all 128 ----
    float* h1s = (float*)(smem + S_H1);
    {
        const int g8 = t >> 4, nl2 = t & 15;
        const float* bias = ws + 13600;
        const float* xsp = xs0 + nl2 * 85;
        for (int gi = g8; gi < 21; gi += 8) {
            float ga = bias[gi], gg = bias[42 + gi], go = bias[63 + gi];
#pragma unroll
            for (int k = 0; k < 84; ++k) {
                const float xv = xsp[k];
                ga += xv * Wih[gi * 84 + k];
                gg += xv * Wih[(42 + gi) * 84 + k];
                go += xv * Wih[(63 + gi) * 84 + k];
            }
            const float c1 = sigmoidf(ga) * tanhf(gg);
            h1s[nl2 * 22 + gi] = sigmoidf(go) * tanhf(c1);
        }
    }
    __syncthreads();

    // ---- phase 5: output projection; thread = nl*7+j, 112 active, coalesced ----
    if (t < 112) {
        const int nl2 = t / 7, j = t - nl2 * 7;
        const float* Wout = ws + 13700;
        float r = ws[13860 + j];
#pragma unroll
        for (int m = 0; m < 21; ++m) r += h1s[nl2 * 22 + m] * Wout[j * 21 + m];
        outp[(size_t)n0 * 7 + t] = r;
    }
}

extern "C" void kernel_launch(void* const* d_in, const int* in_sizes, int n_in,
                              void* d_out, int out_size, void* d_ws, size_t ws_size,
                              hipStream_t stream) {
    const int N = in_sizes[0] / F1260;

    const float* x        = (const float*)d_in[0];
    const float* bn_gamma = (const float*)d_in[1];
    const float* bn_beta  = (const float*)d_in[2];
    const float* W1       = (const float*)d_in[3];
    const float* a1       = (const float*)d_in[4];
    const float* B1       = (const float*)d_in[5];
    const float* W2       = (const float*)d_in[6];
    const float* a2       = (const float*)d_in[7];
    const float* B2       = (const float*)d_in[8];
    const float* W_ih     = (const float*)d_in[9];
    // d_in[10] = W_hh unused (h0 = 0 -> only LSTM step 0 matters)
    const float* b_ih     = (const float*)d_in[11];
    const float* b_hh     = (const float*)d_in[12];
    const float* W_out    = (const float*)d_in[13];
    const float* b_out    = (const float*)d_in[14];

    float* wsf = (float*)d_ws;

    hipMemsetAsync(d_ws, 0, 2560 * sizeof(float), stream);   // zero fsum/fsq

    kA_stats<<<dim3(N / 32), dim3(320), 0, stream>>>(x, wsf, N);
    kB_setup<<<dim3(1), dim3(256), 0, stream>>>(bn_gamma, bn_beta, W1, a1, B1,
                                                W2, a2, B2, b_ih, b_hh,
                                                W_out, b_out, wsf, N);
    kC_main<<<dim3(N / 16), dim3(128), 0, stream>>>(x, wsf, W_ih, (float*)d_out, N);
}